// Round 2
// baseline (700.711 us; speedup 1.0000x reference)
//
#include <hip/hip_runtime.h>
#include <stdint.h>

#define NDIM 1024
#define CTXD 768
#define NH 16
#define HD 64
#define BB 4
#define TT 2048
#define SS 2048
#define L2E 1.44269504f

typedef unsigned short u16;
typedef __bf16 bf16x8 __attribute__((ext_vector_type(8)));
typedef float f32x4 __attribute__((ext_vector_type(4)));

__device__ __forceinline__ u16 f2bf(float f) {
  uint32_t u = __float_as_uint(f);
  u += 0x7fffu + ((u >> 16) & 1u);   // RTNE (inputs finite, no NaN)
  return (u16)(u >> 16);
}

__device__ __forceinline__ void gload16(const void* g, void* l) {
  __builtin_amdgcn_global_load_lds((const __attribute__((address_space(1))) void*)g,
                                   (__attribute__((address_space(3))) void*)l,
                                   16, 0, 0);
}

// ---------------- fp32 -> bf16 elementwise convert ----------------
__global__ void conv_bf16_k(const float* __restrict__ in, u16* __restrict__ out, int n4) {
  int i = blockIdx.x * blockDim.x + threadIdx.x;
  int stride = gridDim.x * blockDim.x;
  for (; i < n4; i += stride) {
    float4 v = ((const float4*)in)[i];
    ushort4 o;
    o.x = f2bf(v.x); o.y = f2bf(v.y); o.z = f2bf(v.z); o.w = f2bf(v.w);
    ((ushort4*)out)[i] = o;
  }
}

// ------------- weight transpose: W (K x N) f32 -> Wt (N x K) bf16 -------------
__global__ void transp_w_k(const float* __restrict__ W, u16* __restrict__ Wt, int K, int N) {
  __shared__ float tile[32][33];
  const int n0 = blockIdx.x * 32, k0 = blockIdx.y * 32;
  const int tx = threadIdx.x, ty = threadIdx.y;  // 32 x 8
  #pragma unroll
  for (int r = 0; r < 4; ++r)
    tile[ty + 8 * r][tx] = W[(size_t)(k0 + ty + 8 * r) * N + n0 + tx];
  __syncthreads();
  #pragma unroll
  for (int r = 0; r < 4; ++r)
    Wt[(size_t)(n0 + ty + 8 * r) * K + k0 + tx] = f2bf(tile[tx][ty + 8 * r]);
}

// ------------- V transpose: v (B*S, DIM) bf16 -> vT (B*NH*HD, S) bf16 -------------
union V16 { uint4 q; u16 h[8]; };
__global__ void transp_v_k(const u16* __restrict__ v, u16* __restrict__ vT) {
  __shared__ u16 tile[64][65];
  const int s0 = blockIdx.x * 64;
  const int bh = blockIdx.y;
  const int b = bh >> 4, h = bh & 15;
  const int t = threadIdx.x;
  #pragma unroll
  for (int it = 0; it < 2; ++it) {
    int u = t + it * 256;
    int row = u >> 3, ch = (u & 7) * 8;
    V16 a;
    a.q = *(const uint4*)&v[(size_t)(b * SS + s0 + row) * NDIM + h * HD + ch];
    #pragma unroll
    for (int e = 0; e < 8; ++e) tile[row][ch + e] = a.h[e];
  }
  __syncthreads();
  #pragma unroll
  for (int it = 0; it < 2; ++it) {
    int u = t + it * 256;
    int d = u >> 3, sch = (u & 7) * 8;
    V16 o;
    #pragma unroll
    for (int e = 0; e < 8; ++e) o.h[e] = tile[sch + e][d];
    *(uint4*)&vT[((size_t)bh * HD + d) * SS + s0 + sch] = o.q;
  }
}

// ------------- bf16 MFMA GEMM: C = A(MxK) * Bt(NxK)^T + bias -------------
// 2-phase double-buffered (T3 minimum recipe): issue next-tile global_load_lds
// before the MFMA block; one __syncthreads() per K-step.
__global__ __launch_bounds__(256, 2) void gemm_bf16_k(
    const u16* __restrict__ A, const u16* __restrict__ Bt,
    const float* __restrict__ bias, void* __restrict__ C,
    int M, int N, int K, float out_scale, int out_f32)
{
  __shared__ __align__(16) u16 As[2][128 * 32];
  __shared__ __align__(16) u16 Bs[2][128 * 32];
  const int tid = threadIdx.x;
  const int w = tid >> 6, l = tid & 63;
  const int lr = l & 15, lg = l >> 4;
  const int brow = blockIdx.y * 128, bcol = blockIdx.x * 128;
  const int wr = (w >> 1) * 64, wc = (w & 1) * 64;

  f32x4 acc[4][4] = {};
  const int srow = l >> 2;           // staging: + c*16
  const int skoff = (l & 3) * 8;

  const int NT = K >> 5;
  int cur = 0;

  // prologue: stage tile 0
  #pragma unroll
  for (int cc = 0; cc < 2; ++cc) {
    int c = 2 * w + cc;
    int row = c * 16 + srow;
    gload16(A  + (size_t)(brow + row) * K + skoff, &As[0][c * 512]);
    gload16(Bt + (size_t)(bcol + row) * K + skoff, &Bs[0][c * 512]);
  }
  __syncthreads();

  for (int t = 0; t < NT; ++t) {
    if (t + 1 < NT) {
      const int k0 = (t + 1) << 5;
      #pragma unroll
      for (int cc = 0; cc < 2; ++cc) {
        int c = 2 * w + cc;
        int row = c * 16 + srow;
        gload16(A  + (size_t)(brow + row) * K + k0 + skoff, &As[cur ^ 1][c * 512]);
        gload16(Bt + (size_t)(bcol + row) * K + k0 + skoff, &Bs[cur ^ 1][c * 512]);
      }
    }
    bf16x8 a[4], b[4];
    #pragma unroll
    for (int m = 0; m < 4; ++m)
      a[m] = *(const bf16x8*)&As[cur][(wr + m * 16 + lr) * 32 + lg * 8];
    #pragma unroll
    for (int n = 0; n < 4; ++n)
      b[n] = *(const bf16x8*)&Bs[cur][(wc + n * 16 + lr) * 32 + lg * 8];
    #pragma unroll
    for (int m = 0; m < 4; ++m)
      #pragma unroll
      for (int n = 0; n < 4; ++n)
        acc[m][n] = __builtin_amdgcn_mfma_f32_16x16x32_bf16(a[m], b[n], acc[m][n], 0, 0, 0);
    __syncthreads();   // drains vmcnt (next tile staged) + lgkmcnt; buffer handoff
    cur ^= 1;
  }

  const int crow0 = brow + wr + lg * 4;
  const int ccol0 = bcol + wc + lr;
  #pragma unroll
  for (int n = 0; n < 4; ++n) {
    const int gc = ccol0 + n * 16;
    const float bn = bias ? bias[gc] : 0.f;
    #pragma unroll
    for (int m = 0; m < 4; ++m) {
      const int gr = crow0 + m * 16;
      #pragma unroll
      for (int r = 0; r < 4; ++r) {
        float v = (acc[m][n][r] + bn) * out_scale;
        if (out_f32) ((float*)C)[(size_t)(gr + r) * N + gc] = v;
        else         ((u16*)C)[(size_t)(gr + r) * N + gc] = f2bf(v);
      }
    }
  }
}

// ------------- flash attention: q,k bf16 (B*T, DIM), vT bf16 (B*NH*HD, S) -------------
// LDS rows are 128B => 16-way bank conflict if linear; XOR-swizzle 16B granules
// (granule ^= row&7), applied both-sides: inverse-swizzled global source for
// global_load_lds (linear dest) + swizzled ds_read / ds_write.
// R2: __launch_bounds__(256,4) (was 2 -> occupancy cap at 22%); per-lane partial
// softmax denominator (one 16-lane reduce at the end instead of per tile);
// T13 defer-max (skip O/l rescale when wave-uniformly mx <= m+8).
__global__ __launch_bounds__(256, 4) void attn_k(
    const u16* __restrict__ q, const u16* __restrict__ k,
    const u16* __restrict__ vT, u16* __restrict__ o)
{
  __shared__ __align__(16) u16 Ks[64 * 64];
  __shared__ __align__(16) u16 Vs[64 * 64];
  __shared__ __align__(16) u16 Ps[4 * 32 * 64];
  const int tid = threadIdx.x, w = tid >> 6, l = tid & 63;
  const int bh = blockIdx.x;
  const int b = bh >> 4, h = bh & 15;
  const int t0 = blockIdx.y * 128 + w * 32;
  const int lr = l & 15, lg = l >> 4;

  bf16x8 aq[2][2];
  #pragma unroll
  for (int m = 0; m < 2; ++m)
    #pragma unroll
    for (int kk = 0; kk < 2; ++kk)
      aq[m][kk] = *(const bf16x8*)&q[(size_t)(b * TT + t0 + m * 16 + lr) * NDIM + h * HD + kk * 32 + lg * 8];

  f32x4 oacc[2][4] = {};
  float mrun[2][4], lpart[2][4];   // lpart: per-lane partial denominator (cols lr,lr+16,lr+32,lr+48)
  #pragma unroll
  for (int m = 0; m < 2; ++m)
    #pragma unroll
    for (int r = 0; r < 4; ++r) { mrun[m][r] = -1e30f; lpart[m][r] = 0.f; }

  const u16* kbase = k + (size_t)b * SS * NDIM + h * HD;
  const u16* vbase = vT + (size_t)bh * HD * SS;
  u16* Pw = &Ps[w * 32 * 64];
  const int sgr = ((l & 7) ^ (l >> 3)) * 8;   // inverse-swizzled source granule

  for (int s0 = 0; s0 < SS; s0 += 64) {
    #pragma unroll
    for (int cc = 0; cc < 2; ++cc) {
      int c = 2 * w + cc;
      int rr = c * 8 + (l >> 3);
      gload16(kbase + (size_t)(s0 + rr) * NDIM + sgr, &Ks[c * 512]);
      gload16(vbase + (size_t)rr * SS + s0 + sgr, &Vs[c * 512]);
    }
    __syncthreads();

    // scores: C[t][s], A=q frags, B=K rows (N x K style)
    f32x4 sc[2][4] = {};
    #pragma unroll
    for (int n = 0; n < 4; ++n) {
      const int srow = n * 16 + lr;
      #pragma unroll
      for (int kk = 0; kk < 2; ++kk) {
        bf16x8 bk = *(const bf16x8*)&Ks[srow * 64 + ((((kk << 2) | lg) ^ (srow & 7)) * 8)];
        #pragma unroll
        for (int m = 0; m < 2; ++m)
          sc[m][n] = __builtin_amdgcn_mfma_f32_16x16x32_bf16(aq[m][kk], bk, sc[m][n], 0, 0, 0);
      }
    }

    // row max (rows are quarter-wave local: row = m*16 + lg*4 + r, col = lr)
    float mx[2][4];
    bool small = true;
    #pragma unroll
    for (int m = 0; m < 2; ++m)
      #pragma unroll
      for (int r = 0; r < 4; ++r) {
        float v = fmaxf(fmaxf(sc[m][0][r], sc[m][1][r]), fmaxf(sc[m][2][r], sc[m][3][r]));
        #pragma unroll
        for (int d = 1; d < 16; d <<= 1) v = fmaxf(v, __shfl_xor(v, d));
        mx[m][r] = v;
        small = small && (v <= mrun[m][r] + 8.f);
      }

    // T13 defer-max: only rescale when some row's max grew by >8
    if (!__all(small)) {
      #pragma unroll
      for (int m = 0; m < 2; ++m)
        #pragma unroll
        for (int r = 0; r < 4; ++r) {
          float mnew = fmaxf(mrun[m][r], mx[m][r]);
          float resc = exp2f((mrun[m][r] - mnew) * L2E);
          mrun[m][r] = mnew;
          lpart[m][r] *= resc;
          #pragma unroll
          for (int n = 0; n < 4; ++n) oacc[m][n][r] *= resc;
        }
    }

    // P = exp(sc - m); accumulate per-lane partial denominator (no per-tile reduce)
    #pragma unroll
    for (int m = 0; m < 2; ++m)
      #pragma unroll
      for (int r = 0; r < 4; ++r) {
        float rs = 0.f;
        #pragma unroll
        for (int n = 0; n < 4; ++n) {
          float p = exp2f((sc[m][n][r] - mrun[m][r]) * L2E);
          sc[m][n][r] = p;
          rs += p;
        }
        lpart[m][r] += rs;
      }

    // P -> LDS (per-wave region), swizzled write
    #pragma unroll
    for (int m = 0; m < 2; ++m)
      #pragma unroll
      for (int n = 0; n < 4; ++n) {
        const int col = n * 16 + lr;
        #pragma unroll
        for (int r = 0; r < 4; ++r) {
          const int row = m * 16 + lg * 4 + r;
          Pw[row * 64 + ((((col >> 3) ^ (row & 7)) * 8) | (col & 7))] = f2bf(sc[m][n][r]);
        }
      }
    asm volatile("s_waitcnt lgkmcnt(0)" ::: "memory");

    // PV: A = P rows (t x s), B = vT rows (d x s)
    #pragma unroll
    for (int kk = 0; kk < 2; ++kk) {
      bf16x8 ap[2];
      #pragma unroll
      for (int m = 0; m < 2; ++m) {
        const int prow = m * 16 + lr;
        ap[m] = *(const bf16x8*)&Pw[prow * 64 + ((((kk << 2) | lg) ^ (prow & 7)) * 8)];
      }
      #pragma unroll
      for (int n = 0; n < 4; ++n) {
        const int drow = n * 16 + lr;
        bf16x8 bv = *(const bf16x8*)&Vs[drow * 64 + ((((kk << 2) | lg) ^ (drow & 7)) * 8)];
        #pragma unroll
        for (int m = 0; m < 2; ++m)
          oacc[m][n] = __builtin_amdgcn_mfma_f32_16x16x32_bf16(ap[m], bv, oacc[m][n], 0, 0, 0);
      }
    }
    __syncthreads();
  }

  // final 16-lane reduce of the partial denominators (once, not per tile)
  #pragma unroll
  for (int m = 0; m < 2; ++m)
    #pragma unroll
    for (int r = 0; r < 4; ++r) {
      float s = lpart[m][r];
      #pragma unroll
      for (int d = 1; d < 16; d <<= 1) s += __shfl_xor(s, d);
      lpart[m][r] = s;
    }

  #pragma unroll
  for (int m = 0; m < 2; ++m)
    #pragma unroll
    for (int n = 0; n < 4; ++n)
      #pragma unroll
      for (int r = 0; r < 4; ++r) {
        float v = oacc[m][n][r] / lpart[m][r];
        o[(size_t)(b * TT + t0 + m * 16 + lg * 4 + r) * NDIM + h * HD + n * 16 + lr] = f2bf(v);
      }
}

extern "C" void kernel_launch(void* const* d_in, const int* in_sizes, int n_in,
                              void* d_out, int out_size, void* d_ws, size_t ws_size,
                              hipStream_t stream) {
  (void)in_sizes; (void)n_in; (void)out_size; (void)ws_size;
  const float* x   = (const float*)d_in[0];
  const float* ctx = (const float*)d_in[1];
  const float* Wq  = (const float*)d_in[2];
  const float* bq  = (const float*)d_in[3];
  const float* Wk  = (const float*)d_in[4];
  const float* bk  = (const float*)d_in[5];
  const float* Wv  = (const float*)d_in[6];
  const float* bv  = (const float*)d_in[7];
  const float* Wo  = (const float*)d_in[8];
  const float* bo  = (const float*)d_in[9];
  float* out = (float*)d_out;

  char* ws = (char*)d_ws;
  size_t off = 0;
  auto alloc = [&](size_t bytes) { void* p = ws + off; off += (bytes + 255) & ~(size_t)255; return p; };
  u16* xb  = (u16*)alloc((size_t)BB * TT * NDIM * 2);
  u16* cb  = (u16*)alloc((size_t)BB * SS * CTXD * 2);
  u16* Wqt = (u16*)alloc((size_t)NDIM * NDIM * 2);
  u16* Wkt = (u16*)alloc((size_t)NDIM * CTXD * 2);
  u16* Wvt = (u16*)alloc((size_t)NDIM * CTXD * 2);
  u16* Wot = (u16*)alloc((size_t)NDIM * NDIM * 2);
  u16* qb  = (u16*)alloc((size_t)BB * TT * NDIM * 2);
  u16* kb  = (u16*)alloc((size_t)BB * SS * NDIM * 2);
  u16* vb  = (u16*)alloc((size_t)BB * SS * NDIM * 2);
  u16* vTb = (u16*)alloc((size_t)BB * SS * NDIM * 2);
  u16* ab  = xb;  // x is dead after the q-projection; reuse for attention output

  conv_bf16_k<<<2048, 256, 0, stream>>>(x, xb, BB * TT * NDIM / 4);
  conv_bf16_k<<<2048, 256, 0, stream>>>(ctx, cb, BB * SS * CTXD / 4);
  transp_w_k<<<dim3(NDIM / 32, NDIM / 32), dim3(32, 8), 0, stream>>>(Wq, Wqt, NDIM, NDIM);
  transp_w_k<<<dim3(NDIM / 32, CTXD / 32), dim3(32, 8), 0, stream>>>(Wk, Wkt, CTXD, NDIM);
  transp_w_k<<<dim3(NDIM / 32, CTXD / 32), dim3(32, 8), 0, stream>>>(Wv, Wvt, CTXD, NDIM);
  transp_w_k<<<dim3(NDIM / 32, NDIM / 32), dim3(32, 8), 0, stream>>>(Wo, Wot, NDIM, NDIM);

  // projections (q pre-scaled by Hd^-0.5 = 0.125, exact in bf16)
  gemm_bf16_k<<<dim3(NDIM / 128, BB * TT / 128), 256, 0, stream>>>(xb, Wqt, bq, qb, BB * TT, NDIM, NDIM, 0.125f, 0);
  gemm_bf16_k<<<dim3(NDIM / 128, BB * SS / 128), 256, 0, stream>>>(cb, Wkt, bk, kb, BB * SS, NDIM, CTXD, 1.f, 0);
  gemm_bf16_k<<<dim3(NDIM / 128, BB * SS / 128), 256, 0, stream>>>(cb, Wvt, bv, vb, BB * SS, NDIM, CTXD, 1.f, 0);

  transp_v_k<<<dim3(SS / 64, BB * NH), 256, 0, stream>>>(vb, vTb);
  attn_k<<<dim3(BB * NH, TT / 128), 256, 0, stream>>>(qb, kb, vTb, ab);

  // output projection, fp32 out
  gemm_bf16_k<<<dim3(NDIM / 128, BB * TT / 128), 256, 0, stream>>>(ab, Wot, bo, out, BB * TT, NDIM, NDIM, 1.f, 1);
}

// Round 3
// 467.417 us; speedup vs baseline: 1.4991x; 1.4991x over previous
//
#include <hip/hip_runtime.h>
#include <stdint.h>

#define NDIM 1024
#define CTXD 768
#define NH 16
#define HD 64
#define BB 4
#define TT 2048
#define SS 2048
#define L2E 1.44269504f

typedef unsigned short u16;
typedef __bf16 bf16x8 __attribute__((ext_vector_type(8)));
typedef float f32x4 __attribute__((ext_vector_type(4)));

__device__ __forceinline__ u16 f2bf(float f) {
  uint32_t u = __float_as_uint(f);
  u += 0x7fffu + ((u >> 16) & 1u);   // RTNE (inputs finite, no NaN)
  return (u16)(u >> 16);
}

__device__ __forceinline__ void gload16(const void* g, void* l) {
  __builtin_amdgcn_global_load_lds((const __attribute__((address_space(1))) void*)g,
                                   (__attribute__((address_space(3))) void*)l,
                                   16, 0, 0);
}

// ---------------- fp32 -> bf16 elementwise convert ----------------
__global__ void conv_bf16_k(const float* __restrict__ in, u16* __restrict__ out, int n4) {
  int i = blockIdx.x * blockDim.x + threadIdx.x;
  int stride = gridDim.x * blockDim.x;
  for (; i < n4; i += stride) {
    float4 v = ((const float4*)in)[i];
    ushort4 o;
    o.x = f2bf(v.x); o.y = f2bf(v.y); o.z = f2bf(v.z); o.w = f2bf(v.w);
    ((ushort4*)out)[i] = o;
  }
}

// ------------- weight transpose: W (K x N) f32 -> Wt (N x K) bf16 -------------
__global__ void transp_w_k(const float* __restrict__ W, u16* __restrict__ Wt, int K, int N) {
  __shared__ float tile[32][33];
  const int n0 = blockIdx.x * 32, k0 = blockIdx.y * 32;
  const int tx = threadIdx.x, ty = threadIdx.y;  // 32 x 8
  #pragma unroll
  for (int r = 0; r < 4; ++r)
    tile[ty + 8 * r][tx] = W[(size_t)(k0 + ty + 8 * r) * N + n0 + tx];
  __syncthreads();
  #pragma unroll
  for (int r = 0; r < 4; ++r)
    Wt[(size_t)(n0 + ty + 8 * r) * K + k0 + tx] = f2bf(tile[tx][ty + 8 * r]);
}

// ------------- V transpose: v (B*S, DIM) bf16 -> vT (B*NH*HD, S) bf16 -------------
union V16 { uint4 q; u16 h[8]; };
__global__ void transp_v_k(const u16* __restrict__ v, u16* __restrict__ vT) {
  __shared__ u16 tile[64][65];
  const int s0 = blockIdx.x * 64;
  const int bh = blockIdx.y;
  const int b = bh >> 4, h = bh & 15;
  const int t = threadIdx.x;
  #pragma unroll
  for (int it = 0; it < 2; ++it) {
    int u = t + it * 256;
    int row = u >> 3, ch = (u & 7) * 8;
    V16 a;
    a.q = *(const uint4*)&v[(size_t)(b * SS + s0 + row) * NDIM + h * HD + ch];
    #pragma unroll
    for (int e = 0; e < 8; ++e) tile[row][ch + e] = a.h[e];
  }
  __syncthreads();
  #pragma unroll
  for (int it = 0; it < 2; ++it) {
    int u = t + it * 256;
    int d = u >> 3, sch = (u & 7) * 8;
    V16 o;
    #pragma unroll
    for (int e = 0; e < 8; ++e) o.h[e] = tile[sch + e][d];
    *(uint4*)&vT[((size_t)bh * HD + d) * SS + s0 + sch] = o.q;
  }
}

// ------------- bf16 MFMA GEMM: C = A(MxK) * Bt(NxK)^T + bias -------------
// R3: back to single-buffer m97 structure (16 KB LDS), bounds(256,3) so
// 3 blocks/CU co-reside (implicit wave-level overlap per m114).
__global__ __launch_bounds__(256, 3) void gemm_bf16_k(
    const u16* __restrict__ A, const u16* __restrict__ Bt,
    const float* __restrict__ bias, void* __restrict__ C,
    int M, int N, int K, float out_scale, int out_f32)
{
  __shared__ __align__(16) u16 As[128 * 32];
  __shared__ __align__(16) u16 Bs[128 * 32];
  const int tid = threadIdx.x;
  const int w = tid >> 6, l = tid & 63;
  const int lr = l & 15, lg = l >> 4;
  const int brow = blockIdx.y * 128, bcol = blockIdx.x * 128;
  const int wr = (w >> 1) * 64, wc = (w & 1) * 64;

  f32x4 acc[4][4] = {};
  const int srow = l >> 2;           // staging: + c*16
  const int skoff = (l & 3) * 8;

  for (int k0 = 0; k0 < K; k0 += 32) {
    #pragma unroll
    for (int cc = 0; cc < 2; ++cc) {
      int c = 2 * w + cc;
      int row = c * 16 + srow;
      gload16(A  + (size_t)(brow + row) * K + k0 + skoff, &As[c * 512]);
      gload16(Bt + (size_t)(bcol + row) * K + k0 + skoff, &Bs[c * 512]);
    }
    __syncthreads();
    bf16x8 a[4], b[4];
    #pragma unroll
    for (int m = 0; m < 4; ++m)
      a[m] = *(const bf16x8*)&As[(wr + m * 16 + lr) * 32 + lg * 8];
    #pragma unroll
    for (int n = 0; n < 4; ++n)
      b[n] = *(const bf16x8*)&Bs[(wc + n * 16 + lr) * 32 + lg * 8];
    #pragma unroll
    for (int m = 0; m < 4; ++m)
      #pragma unroll
      for (int n = 0; n < 4; ++n)
        acc[m][n] = __builtin_amdgcn_mfma_f32_16x16x32_bf16(a[m], b[n], acc[m][n], 0, 0, 0);
    __syncthreads();
  }

  const int crow0 = brow + wr + lg * 4;
  const int ccol0 = bcol + wc + lr;
  #pragma unroll
  for (int n = 0; n < 4; ++n) {
    const int gc = ccol0 + n * 16;
    const float bn = bias ? bias[gc] : 0.f;
    #pragma unroll
    for (int m = 0; m < 4; ++m) {
      const int gr = crow0 + m * 16;
      #pragma unroll
      for (int r = 0; r < 4; ++r) {
        float v = (acc[m][n][r] + bn) * out_scale;
        if (out_f32) ((float*)C)[(size_t)(gr + r) * N + gc] = v;
        else         ((u16*)C)[(size_t)(gr + r) * N + gc] = f2bf(v);
      }
    }
  }
}

// ------------- flash attention: q,k bf16 (B*T, DIM), vT bf16 (B*NH*HD, S) -------------
// LDS rows are 128B => 16-way bank conflict if linear; XOR-swizzle 16B granules
// (granule ^= row&7), both-sides: inverse-swizzled global source for
// global_load_lds (linear dest) + swizzled ds_read / ds_write.
// R3: bounds(256,3) -> VGPR cap 160, NO spills (R2's bounds(256,4) forced
// VGPR=64 -> 670 MB of scratch spill traffic, 1.5x slowdown). 3 blocks/CU.
__global__ __launch_bounds__(256, 3) void attn_k(
    const u16* __restrict__ q, const u16* __restrict__ k,
    const u16* __restrict__ vT, u16* __restrict__ o)
{
  __shared__ __align__(16) u16 Ks[64 * 64];
  __shared__ __align__(16) u16 Vs[64 * 64];
  __shared__ __align__(16) u16 Ps[4 * 32 * 64];
  const int tid = threadIdx.x, w = tid >> 6, l = tid & 63;
  const int bh = blockIdx.x;
  const int b = bh >> 4, h = bh & 15;
  const int t0 = blockIdx.y * 128 + w * 32;
  const int lr = l & 15, lg = l >> 4;

  bf16x8 aq[2][2];
  #pragma unroll
  for (int m = 0; m < 2; ++m)
    #pragma unroll
    for (int kk = 0; kk < 2; ++kk)
      aq[m][kk] = *(const bf16x8*)&q[(size_t)(b * TT + t0 + m * 16 + lr) * NDIM + h * HD + kk * 32 + lg * 8];

  f32x4 oacc[2][4] = {};
  float mrun[2][4], lpart[2][4];   // lpart: per-lane partial denominator (col lr of each n-frag)
  #pragma unroll
  for (int m = 0; m < 2; ++m)
    #pragma unroll
    for (int r = 0; r < 4; ++r) { mrun[m][r] = -1e30f; lpart[m][r] = 0.f; }

  const u16* kbase = k + (size_t)b * SS * NDIM + h * HD;
  const u16* vbase = vT + (size_t)bh * HD * SS;
  u16* Pw = &Ps[w * 32 * 64];
  const int sgr = ((l & 7) ^ (l >> 3)) * 8;   // inverse-swizzled source granule

  for (int s0 = 0; s0 < SS; s0 += 64) {
    #pragma unroll
    for (int cc = 0; cc < 2; ++cc) {
      int c = 2 * w + cc;
      int rr = c * 8 + (l >> 3);
      gload16(kbase + (size_t)(s0 + rr) * NDIM + sgr, &Ks[c * 512]);
      gload16(vbase + (size_t)rr * SS + s0 + sgr, &Vs[c * 512]);
    }
    __syncthreads();

    // scores: C[t][s], A=q frags, B=K rows (N x K style)
    f32x4 sc[2][4] = {};
    #pragma unroll
    for (int n = 0; n < 4; ++n) {
      const int srow = n * 16 + lr;
      #pragma unroll
      for (int kk = 0; kk < 2; ++kk) {
        bf16x8 bk = *(const bf16x8*)&Ks[srow * 64 + ((((kk << 2) | lg) ^ (srow & 7)) * 8)];
        #pragma unroll
        for (int m = 0; m < 2; ++m)
          sc[m][n] = __builtin_amdgcn_mfma_f32_16x16x32_bf16(aq[m][kk], bk, sc[m][n], 0, 0, 0);
      }
    }

    // row max + T13 defer-max (rows quarter-wave local: row = m*16+lg*4+r, col = lr)
    bool small = true;
    float mx[2][4];
    #pragma unroll
    for (int m = 0; m < 2; ++m)
      #pragma unroll
      for (int r = 0; r < 4; ++r) {
        float v = fmaxf(fmaxf(sc[m][0][r], sc[m][1][r]), fmaxf(sc[m][2][r], sc[m][3][r]));
        #pragma unroll
        for (int d = 1; d < 16; d <<= 1) v = fmaxf(v, __shfl_xor(v, d));
        mx[m][r] = v;
        small = small && (v <= mrun[m][r] + 8.f);
      }

    if (!__all(small)) {
      #pragma unroll
      for (int m = 0; m < 2; ++m)
        #pragma unroll
        for (int r = 0; r < 4; ++r) {
          float mnew = fmaxf(mrun[m][r], mx[m][r]);
          float resc = exp2f((mrun[m][r] - mnew) * L2E);
          mrun[m][r] = mnew;
          lpart[m][r] *= resc;
          #pragma unroll
          for (int n = 0; n < 4; ++n) oacc[m][n][r] *= resc;
        }
    }

    // P = exp(sc - m); per-lane partial denominator (no per-tile reduce)
    #pragma unroll
    for (int m = 0; m < 2; ++m)
      #pragma unroll
      for (int r = 0; r < 4; ++r) {
        float rs = 0.f;
        #pragma unroll
        for (int n = 0; n < 4; ++n) {
          float p = exp2f((sc[m][n][r] - mrun[m][r]) * L2E);
          sc[m][n][r] = p;
          rs += p;
        }
        lpart[m][r] += rs;
      }

    // P -> LDS (per-wave region), swizzled write
    #pragma unroll
    for (int m = 0; m < 2; ++m)
      #pragma unroll
      for (int n = 0; n < 4; ++n) {
        const int col = n * 16 + lr;
        #pragma unroll
        for (int r = 0; r < 4; ++r) {
          const int row = m * 16 + lg * 4 + r;
          Pw[row * 64 + ((((col >> 3) ^ (row & 7)) * 8) | (col & 7))] = f2bf(sc[m][n][r]);
        }
      }
    asm volatile("s_waitcnt lgkmcnt(0)" ::: "memory");

    // PV: A = P rows (t x s), B = vT rows (d x s)
    #pragma unroll
    for (int kk = 0; kk < 2; ++kk) {
      bf16x8 ap[2];
      #pragma unroll
      for (int m = 0; m < 2; ++m) {
        const int prow = m * 16 + lr;
        ap[m] = *(const bf16x8*)&Pw[prow * 64 + ((((kk << 2) | lg) ^ (prow & 7)) * 8)];
      }
      #pragma unroll
      for (int n = 0; n < 4; ++n) {
        const int drow = n * 16 + lr;
        bf16x8 bv = *(const bf16x8*)&Vs[drow * 64 + ((((kk << 2) | lg) ^ (drow & 7)) * 8)];
        #pragma unroll
        for (int m = 0; m < 2; ++m)
          oacc[m][n] = __builtin_amdgcn_mfma_f32_16x16x32_bf16(ap[m], bv, oacc[m][n], 0, 0, 0);
      }
    }
    __syncthreads();
  }

  // final 16-lane reduce of the partial denominators (once, not per tile)
  #pragma unroll
  for (int m = 0; m < 2; ++m)
    #pragma unroll
    for (int r = 0; r < 4; ++r) {
      float s = lpart[m][r];
      #pragma unroll
      for (int d = 1; d < 16; d <<= 1) s += __shfl_xor(s, d);
      lpart[m][r] = s;
    }

  #pragma unroll
  for (int m = 0; m < 2; ++m)
    #pragma unroll
    for (int n = 0; n < 4; ++n)
      #pragma unroll
      for (int r = 0; r < 4; ++r) {
        float v = oacc[m][n][r] / lpart[m][r];
        o[(size_t)(b * TT + t0 + m * 16 + lg * 4 + r) * NDIM + h * HD + n * 16 + lr] = f2bf(v);
      }
}

extern "C" void kernel_launch(void* const* d_in, const int* in_sizes, int n_in,
                              void* d_out, int out_size, void* d_ws, size_t ws_size,
                              hipStream_t stream) {
  (void)in_sizes; (void)n_in; (void)out_size; (void)ws_size;
  const float* x   = (const float*)d_in[0];
  const float* ctx = (const float*)d_in[1];
  const float* Wq  = (const float*)d_in[2];
  const float* bq  = (const float*)d_in[3];
  const float* Wk  = (const float*)d_in[4];
  const float* bk  = (const float*)d_in[5];
  const float* Wv  = (const float*)d_in[6];
  const float* bv  = (const float*)d_in[7];
  const float* Wo  = (const float*)d_in[8];
  const float* bo  = (const float*)d_in[9];
  float* out = (float*)d_out;

  char* ws = (char*)d_ws;
  size_t off = 0;
  auto alloc = [&](size_t bytes) { void* p = ws + off; off += (bytes + 255) & ~(size_t)255; return p; };
  u16* xb  = (u16*)alloc((size_t)BB * TT * NDIM * 2);
  u16* cb  = (u16*)alloc((size_t)BB * SS * CTXD * 2);
  u16* Wqt = (u16*)alloc((size_t)NDIM * NDIM * 2);
  u16* Wkt = (u16*)alloc((size_t)NDIM * CTXD * 2);
  u16* Wvt = (u16*)alloc((size_t)NDIM * CTXD * 2);
  u16* Wot = (u16*)alloc((size_t)NDIM * NDIM * 2);
  u16* qb  = (u16*)alloc((size_t)BB * TT * NDIM * 2);
  u16* kb  = (u16*)alloc((size_t)BB * SS * NDIM * 2);
  u16* vb  = (u16*)alloc((size_t)BB * SS * NDIM * 2);
  u16* vTb = (u16*)alloc((size_t)BB * SS * NDIM * 2);
  u16* ab  = xb;  // x is dead after the q-projection; reuse for attention output

  conv_bf16_k<<<2048, 256, 0, stream>>>(x, xb, BB * TT * NDIM / 4);
  conv_bf16_k<<<2048, 256, 0, stream>>>(ctx, cb, BB * SS * CTXD / 4);
  transp_w_k<<<dim3(NDIM / 32, NDIM / 32), dim3(32, 8), 0, stream>>>(Wq, Wqt, NDIM, NDIM);
  transp_w_k<<<dim3(NDIM / 32, CTXD / 32), dim3(32, 8), 0, stream>>>(Wk, Wkt, CTXD, NDIM);
  transp_w_k<<<dim3(NDIM / 32, CTXD / 32), dim3(32, 8), 0, stream>>>(Wv, Wvt, CTXD, NDIM);
  transp_w_k<<<dim3(NDIM / 32, NDIM / 32), dim3(32, 8), 0, stream>>>(Wo, Wot, NDIM, NDIM);

  // projections (q pre-scaled by Hd^-0.5 = 0.125, exact in bf16)
  gemm_bf16_k<<<dim3(NDIM / 128, BB * TT / 128), 256, 0, stream>>>(xb, Wqt, bq, qb, BB * TT, NDIM, NDIM, 0.125f, 0);
  gemm_bf16_k<<<dim3(NDIM / 128, BB * SS / 128), 256, 0, stream>>>(cb, Wkt, bk, kb, BB * SS, NDIM, CTXD, 1.f, 0);
  gemm_bf16_k<<<dim3(NDIM / 128, BB * SS / 128), 256, 0, stream>>>(cb, Wvt, bv, vb, BB * SS, NDIM, CTXD, 1.f, 0);

  transp_v_k<<<dim3(SS / 64, BB * NH), 256, 0, stream>>>(vb, vTb);
  attn_k<<<dim3(BB * NH, TT / 128), 256, 0, stream>>>(qb, kb, vTb, ab);

  // output projection, fp32 out
  gemm_bf16_k<<<dim3(NDIM / 128, BB * TT / 128), 256, 0, stream>>>(ab, Wot, bo, out, BB * TT, NDIM, NDIM, 1.f, 1);
}

// Round 4
// 389.244 us; speedup vs baseline: 1.8002x; 1.2008x over previous
//
#include <hip/hip_runtime.h>
#include <stdint.h>

#define NDIM 1024
#define CTXD 768
#define NH 16
#define HD 64
#define BB 4
#define TT 2048
#define SS 2048
#define L2E 1.44269504f

typedef unsigned short u16;
typedef __bf16 bf16x8 __attribute__((ext_vector_type(8)));
typedef float f32x4 __attribute__((ext_vector_type(4)));

__device__ __forceinline__ u16 f2bf(float f) {
  uint32_t u = __float_as_uint(f);
  u += 0x7fffu + ((u >> 16) & 1u);   // RTNE (inputs finite, no NaN)
  return (u16)(u >> 16);
}

// hardware RTNE convert (lowers to v_cvt_pk_bf16_f32)
__device__ __forceinline__ u16 bfcast(float f) {
  union { __bf16 b; u16 u; } cv;
  cv.b = (__bf16)f;
  return cv.u;
}

__device__ __forceinline__ void gload16(const void* g, void* l) {
  __builtin_amdgcn_global_load_lds((const __attribute__((address_space(1))) void*)g,
                                   (__attribute__((address_space(3))) void*)l,
                                   16, 0, 0);
}

// ---------------- fp32 -> bf16 elementwise convert ----------------
__global__ void conv_bf16_k(const float* __restrict__ in, u16* __restrict__ out, int n4) {
  int i = blockIdx.x * blockDim.x + threadIdx.x;
  int stride = gridDim.x * blockDim.x;
  for (; i < n4; i += stride) {
    float4 v = ((const float4*)in)[i];
    ushort4 o;
    o.x = f2bf(v.x); o.y = f2bf(v.y); o.z = f2bf(v.z); o.w = f2bf(v.w);
    ((ushort4*)out)[i] = o;
  }
}

// ------------- weight transpose: W (K x N) f32 -> Wt (N x K) bf16 -------------
__global__ void transp_w_k(const float* __restrict__ W, u16* __restrict__ Wt, int K, int N) {
  __shared__ float tile[32][33];
  const int n0 = blockIdx.x * 32, k0 = blockIdx.y * 32;
  const int tx = threadIdx.x, ty = threadIdx.y;  // 32 x 8
  #pragma unroll
  for (int r = 0; r < 4; ++r)
    tile[ty + 8 * r][tx] = W[(size_t)(k0 + ty + 8 * r) * N + n0 + tx];
  __syncthreads();
  #pragma unroll
  for (int r = 0; r < 4; ++r)
    Wt[(size_t)(n0 + ty + 8 * r) * K + k0 + tx] = f2bf(tile[tx][ty + 8 * r]);
}

// ------------- V transpose: v (B*S, DIM) bf16 -> vT (B*NH*HD, S) bf16 -------------
union V16 { uint4 q; u16 h[8]; };
__global__ void transp_v_k(const u16* __restrict__ v, u16* __restrict__ vT) {
  __shared__ u16 tile[64][65];
  const int s0 = blockIdx.x * 64;
  const int bh = blockIdx.y;
  const int b = bh >> 4, h = bh & 15;
  const int t = threadIdx.x;
  #pragma unroll
  for (int it = 0; it < 2; ++it) {
    int u = t + it * 256;
    int row = u >> 3, ch = (u & 7) * 8;
    V16 a;
    a.q = *(const uint4*)&v[(size_t)(b * SS + s0 + row) * NDIM + h * HD + ch];
    #pragma unroll
    for (int e = 0; e < 8; ++e) tile[row][ch + e] = a.h[e];
  }
  __syncthreads();
  #pragma unroll
  for (int it = 0; it < 2; ++it) {
    int u = t + it * 256;
    int d = u >> 3, sch = (u & 7) * 8;
    V16 o;
    #pragma unroll
    for (int e = 0; e < 8; ++e) o.h[e] = tile[sch + e][d];
    *(uint4*)&vT[((size_t)bh * HD + d) * SS + s0 + sch] = o.q;
  }
}

// ------------- bf16 MFMA GEMM: C = A(MxK) * Bt(NxK)^T + bias -------------
// single-buffer m97 structure (16 KB LDS), bounds(256,3): 3 blocks/CU.
__global__ __launch_bounds__(256, 3) void gemm_bf16_k(
    const u16* __restrict__ A, const u16* __restrict__ Bt,
    const float* __restrict__ bias, void* __restrict__ C,
    int M, int N, int K, float out_scale, int out_f32)
{
  __shared__ __align__(16) u16 As[128 * 32];
  __shared__ __align__(16) u16 Bs[128 * 32];
  const int tid = threadIdx.x;
  const int w = tid >> 6, l = tid & 63;
  const int lr = l & 15, lg = l >> 4;
  const int brow = blockIdx.y * 128, bcol = blockIdx.x * 128;
  const int wr = (w >> 1) * 64, wc = (w & 1) * 64;

  f32x4 acc[4][4] = {};
  const int srow = l >> 2;           // staging: + c*16
  const int skoff = (l & 3) * 8;

  for (int k0 = 0; k0 < K; k0 += 32) {
    #pragma unroll
    for (int cc = 0; cc < 2; ++cc) {
      int c = 2 * w + cc;
      int row = c * 16 + srow;
      gload16(A  + (size_t)(brow + row) * K + k0 + skoff, &As[c * 512]);
      gload16(Bt + (size_t)(bcol + row) * K + k0 + skoff, &Bs[c * 512]);
    }
    __syncthreads();
    bf16x8 a[4], b[4];
    #pragma unroll
    for (int m = 0; m < 4; ++m)
      a[m] = *(const bf16x8*)&As[(wr + m * 16 + lr) * 32 + lg * 8];
    #pragma unroll
    for (int n = 0; n < 4; ++n)
      b[n] = *(const bf16x8*)&Bs[(wc + n * 16 + lr) * 32 + lg * 8];
    #pragma unroll
    for (int m = 0; m < 4; ++m)
      #pragma unroll
      for (int n = 0; n < 4; ++n)
        acc[m][n] = __builtin_amdgcn_mfma_f32_16x16x32_bf16(a[m], b[n], acc[m][n], 0, 0, 0);
    __syncthreads();
  }

  const int crow0 = brow + wr + lg * 4;
  const int ccol0 = bcol + wc + lr;
  #pragma unroll
  for (int n = 0; n < 4; ++n) {
    const int gc = ccol0 + n * 16;
    const float bn = bias ? bias[gc] : 0.f;
    #pragma unroll
    for (int m = 0; m < 4; ++m) {
      const int gr = crow0 + m * 16;
      #pragma unroll
      for (int r = 0; r < 4; ++r) {
        float v = (acc[m][n][r] + bn) * out_scale;
        if (out_f32) ((float*)C)[(size_t)(gr + r) * N + gc] = v;
        else         ((u16*)C)[(size_t)(gr + r) * N + gc] = f2bf(v);
      }
    }
  }
}

// ------------- flash attention: q,k bf16 (B*T, DIM), vT bf16 (B*NH*HD, S) -------------
// R4: (1) K/V double-buffer, 1 barrier/tile (stage t+1 before compute of t);
//     (2) swapped QK^T: mfma(K,Q) -> D rows=s, cols=t; each lane's P values
//         share its own t => in-lane row-max/denom (15 fmax + 2 shfl), P-write
//         as 8x ds_write_b64 of 4 consecutive s (was 32x b16), paired cvt_pk;
//     (3) T5 setprio around MFMA clusters.
// P LDS layout [t][64 s] + 16B-granule XOR swizzle identical to R3 (reads unchanged).
__global__ __launch_bounds__(256, 3) void attn_k(
    const u16* __restrict__ q, const u16* __restrict__ k,
    const u16* __restrict__ vT, u16* __restrict__ o)
{
  __shared__ __align__(16) u16 Ks[2][64 * 64];
  __shared__ __align__(16) u16 Vs[2][64 * 64];
  __shared__ __align__(16) u16 Ps[4 * 32 * 64];
  const int tid = threadIdx.x, w = tid >> 6, l = tid & 63;
  const int bh = blockIdx.x;
  const int b = bh >> 4, h = bh & 15;
  const int t0 = blockIdx.y * 128 + w * 32;
  const int lr = l & 15, lg = l >> 4;

  bf16x8 aq[2][2];
  #pragma unroll
  for (int tn = 0; tn < 2; ++tn)
    #pragma unroll
    for (int kk = 0; kk < 2; ++kk)
      aq[tn][kk] = *(const bf16x8*)&q[(size_t)(b * TT + t0 + tn * 16 + lr) * NDIM + h * HD + kk * 32 + lg * 8];

  f32x4 oacc[2][4] = {};
  float mrun[2] = {-1e30f, -1e30f};   // running max for rows t = tn*16 + lr
  float lpart[2] = {0.f, 0.f};        // per-lane partial denominator (this lg group's s-slice)

  const u16* kbase = k + (size_t)b * SS * NDIM + h * HD;
  const u16* vbase = vT + (size_t)bh * HD * SS;
  u16* Pw = &Ps[w * 32 * 64];
  const int sgr = ((l & 7) ^ (l >> 3)) * 8;   // inverse-swizzled source granule

  auto stage = [&](int s0, int buf) {
    #pragma unroll
    for (int cc = 0; cc < 2; ++cc) {
      int c = 2 * w + cc;
      int rr = c * 8 + (l >> 3);
      gload16(kbase + (size_t)(s0 + rr) * NDIM + sgr, &Ks[buf][c * 512]);
      gload16(vbase + (size_t)rr * SS + s0 + sgr, &Vs[buf][c * 512]);
    }
  };

  stage(0, 0);
  __syncthreads();
  int cur = 0;

  for (int s0 = 0; s0 < SS; s0 += 64) {
    if (s0 + 64 < SS) stage(s0 + 64, cur ^ 1);   // prefetch; in flight under compute

    // QK^T swapped: sc[sm][tn]: s = sm*16 + lg*4 + r, t = tn*16 + lr
    f32x4 sc[4][2] = {};
    __builtin_amdgcn_s_setprio(1);
    #pragma unroll
    for (int sm = 0; sm < 4; ++sm) {
      const int srow = sm * 16 + lr;
      #pragma unroll
      for (int kk = 0; kk < 2; ++kk) {
        bf16x8 ak = *(const bf16x8*)&Ks[cur][srow * 64 + ((((kk << 2) | lg) ^ (srow & 7)) * 8)];
        #pragma unroll
        for (int tn = 0; tn < 2; ++tn)
          sc[sm][tn] = __builtin_amdgcn_mfma_f32_16x16x32_bf16(ak, aq[tn][kk], sc[sm][tn], 0, 0, 0);
      }
    }
    __builtin_amdgcn_s_setprio(0);

    // per-row max: in-lane over 16 values, then across the 4 lg groups
    float pmax[2];
    #pragma unroll
    for (int tn = 0; tn < 2; ++tn) {
      float v = sc[0][tn][0];
      #pragma unroll
      for (int sm = 0; sm < 4; ++sm)
        #pragma unroll
        for (int r = 0; r < 4; ++r) v = fmaxf(v, sc[sm][tn][r]);
      v = fmaxf(v, __shfl_xor(v, 16));
      v = fmaxf(v, __shfl_xor(v, 32));
      pmax[tn] = v;
    }

    // T13 defer-max: rescale only when some row's max grew by >8
    bool ok = (pmax[0] <= mrun[0] + 8.f) && (pmax[1] <= mrun[1] + 8.f);
    if (!__all(ok)) {
      float rsc[2];
      #pragma unroll
      for (int tn = 0; tn < 2; ++tn) {
        float mnew = fmaxf(mrun[tn], pmax[tn]);
        rsc[tn] = exp2f((mrun[tn] - mnew) * L2E);
        mrun[tn] = mnew;
        lpart[tn] *= rsc[tn];
      }
      // oacc rows are t = m*16 + lg*4 + r -> broadcast resc from lane (lg*4+r)
      #pragma unroll
      for (int m = 0; m < 2; ++m)
        #pragma unroll
        for (int r = 0; r < 4; ++r) {
          float rb = __shfl(rsc[m], lg * 4 + r);
          #pragma unroll
          for (int n = 0; n < 4; ++n) oacc[m][n][r] *= rb;
        }
    }

    // exp, partial denominator, P -> LDS as b64 runs of 4 consecutive s
    #pragma unroll
    for (int tn = 0; tn < 2; ++tn) {
      const int prow = tn * 16 + lr;
      const int rsw = prow & 7;
      u16* pr = &Pw[prow * 64 + (lg & 1) * 4];
      float ls = 0.f;
      #pragma unroll
      for (int sm = 0; sm < 4; ++sm) {
        union { ushort4 v; u16 e[4]; } pk;
        #pragma unroll
        for (int r = 0; r < 4; ++r) {
          float p = exp2f((sc[sm][tn][r] - mrun[tn]) * L2E);
          ls += p;
          pk.e[r] = bfcast(p);
        }
        const int g = sm * 2 + (lg >> 1);
        *(ushort4*)&pr[(g ^ rsw) * 8] = pk.v;
      }
      lpart[tn] += ls;
    }
    asm volatile("s_waitcnt lgkmcnt(0)" ::: "memory");
    __builtin_amdgcn_sched_barrier(0);

    // PV: A = P rows (t x s), B = vT rows (d x s) -- reads identical to R3
    __builtin_amdgcn_s_setprio(1);
    #pragma unroll
    for (int kk = 0; kk < 2; ++kk) {
      bf16x8 ap[2];
      #pragma unroll
      for (int m = 0; m < 2; ++m) {
        const int prow = m * 16 + lr;
        ap[m] = *(const bf16x8*)&Pw[prow * 64 + ((((kk << 2) | lg) ^ (prow & 7)) * 8)];
      }
      #pragma unroll
      for (int n = 0; n < 4; ++n) {
        const int drow = n * 16 + lr;
        bf16x8 bv = *(const bf16x8*)&Vs[cur][drow * 64 + ((((kk << 2) | lg) ^ (drow & 7)) * 8)];
        #pragma unroll
        for (int m = 0; m < 2; ++m)
          oacc[m][n] = __builtin_amdgcn_mfma_f32_16x16x32_bf16(ap[m], bv, oacc[m][n], 0, 0, 0);
      }
    }
    __builtin_amdgcn_s_setprio(0);
    __syncthreads();   // drains vmcnt (prefetch done) + lgkm; buffer handoff
    cur ^= 1;
  }

  // full row denominators (reduce the 4 lg partials), then divide & store
  float red[2];
  #pragma unroll
  for (int tn = 0; tn < 2; ++tn) {
    float s = lpart[tn];
    s += __shfl_xor(s, 16);
    s += __shfl_xor(s, 32);
    red[tn] = s;
  }
  #pragma unroll
  for (int m = 0; m < 2; ++m)
    #pragma unroll
    for (int r = 0; r < 4; ++r) {
      float den = __shfl(red[m], lg * 4 + r);
      float inv = 1.f / den;
      #pragma unroll
      for (int n = 0; n < 4; ++n) {
        float v = oacc[m][n][r] * inv;
        o[(size_t)(b * TT + t0 + m * 16 + lg * 4 + r) * NDIM + h * HD + n * 16 + lr] = bfcast(v);
      }
    }
}

extern "C" void kernel_launch(void* const* d_in, const int* in_sizes, int n_in,
                              void* d_out, int out_size, void* d_ws, size_t ws_size,
                              hipStream_t stream) {
  (void)in_sizes; (void)n_in; (void)out_size; (void)ws_size;
  const float* x   = (const float*)d_in[0];
  const float* ctx = (const float*)d_in[1];
  const float* Wq  = (const float*)d_in[2];
  const float* bq  = (const float*)d_in[3];
  const float* Wk  = (const float*)d_in[4];
  const float* bk  = (const float*)d_in[5];
  const float* Wv  = (const float*)d_in[6];
  const float* bv  = (const float*)d_in[7];
  const float* Wo  = (const float*)d_in[8];
  const float* bo  = (const float*)d_in[9];
  float* out = (float*)d_out;

  char* ws = (char*)d_ws;
  size_t off = 0;
  auto alloc = [&](size_t bytes) { void* p = ws + off; off += (bytes + 255) & ~(size_t)255; return p; };
  u16* xb  = (u16*)alloc((size_t)BB * TT * NDIM * 2);
  u16* cb  = (u16*)alloc((size_t)BB * SS * CTXD * 2);
  u16* Wqt = (u16*)alloc((size_t)NDIM * NDIM * 2);
  u16* Wkt = (u16*)alloc((size_t)NDIM * CTXD * 2);
  u16* Wvt = (u16*)alloc((size_t)NDIM * CTXD * 2);
  u16* Wot = (u16*)alloc((size_t)NDIM * NDIM * 2);
  u16* qb  = (u16*)alloc((size_t)BB * TT * NDIM * 2);
  u16* kb  = (u16*)alloc((size_t)BB * SS * NDIM * 2);
  u16* vb  = (u16*)alloc((size_t)BB * SS * NDIM * 2);
  u16* vTb = (u16*)alloc((size_t)BB * SS * NDIM * 2);
  u16* ab  = xb;  // x is dead after the q-projection; reuse for attention output

  conv_bf16_k<<<2048, 256, 0, stream>>>(x, xb, BB * TT * NDIM / 4);
  conv_bf16_k<<<2048, 256, 0, stream>>>(ctx, cb, BB * SS * CTXD / 4);
  transp_w_k<<<dim3(NDIM / 32, NDIM / 32), dim3(32, 8), 0, stream>>>(Wq, Wqt, NDIM, NDIM);
  transp_w_k<<<dim3(NDIM / 32, CTXD / 32), dim3(32, 8), 0, stream>>>(Wk, Wkt, CTXD, NDIM);
  transp_w_k<<<dim3(NDIM / 32, CTXD / 32), dim3(32, 8), 0, stream>>>(Wv, Wvt, CTXD, NDIM);
  transp_w_k<<<dim3(NDIM / 32, NDIM / 32), dim3(32, 8), 0, stream>>>(Wo, Wot, NDIM, NDIM);

  // projections (q pre-scaled by Hd^-0.5 = 0.125, exact in bf16)
  gemm_bf16_k<<<dim3(NDIM / 128, BB * TT / 128), 256, 0, stream>>>(xb, Wqt, bq, qb, BB * TT, NDIM, NDIM, 0.125f, 0);
  gemm_bf16_k<<<dim3(NDIM / 128, BB * SS / 128), 256, 0, stream>>>(cb, Wkt, bk, kb, BB * SS, NDIM, CTXD, 1.f, 0);
  gemm_bf16_k<<<dim3(NDIM / 128, BB * SS / 128), 256, 0, stream>>>(cb, Wvt, bv, vb, BB * SS, NDIM, CTXD, 1.f, 0);

  transp_v_k<<<dim3(SS / 64, BB * NH), 256, 0, stream>>>(vb, vTb);
  attn_k<<<dim3(BB * NH, TT / 128), 256, 0, stream>>>(qb, kb, vTb, ab);

  // output projection, fp32 out
  gemm_bf16_k<<<dim3(NDIM / 128, BB * TT / 128), 256, 0, stream>>>(ab, Wot, bo, out, BB * TT, NDIM, NDIM, 1.f, 1);
}